// Round 5
// baseline (229.207 us; speedup 1.0000x reference)
//
#include <hip/hip_runtime.h>
#include <hip/hip_bf16.h>

typedef unsigned short bf16_t;
typedef __attribute__((ext_vector_type(8))) short bf16x8;
typedef __attribute__((ext_vector_type(4))) float f32x4;

#define MFMA16(a, b, c) __builtin_amdgcn_mfma_f32_16x16x32_bf16((a), (b), (c), 0, 0, 0)

__device__ __forceinline__ bf16_t f2bf(float f) {
  union { float f; unsigned u; } v; v.f = f;
  unsigned u = v.u;
  u += 0x7FFFu + ((u >> 16) & 1u);
  return (bf16_t)(u >> 16);
}

__device__ __forceinline__ void gld_lds16(const void* g, void* l) {
  __builtin_amdgcn_global_load_lds(
      (const __attribute__((address_space(1))) unsigned int*)g,
      (__attribute__((address_space(3))) unsigned int*)l, 16, 0, 0);
}

// ---------------- elementwise fp32 -> bf16 (8/thread) ----------------
__global__ __launch_bounds__(256) void k_f32_to_bf16(const float* __restrict__ in,
                                                     bf16_t* __restrict__ out, int n8) {
  int i = blockIdx.x * 256 + threadIdx.x;
  if (i >= n8) return;
  const float4* p = (const float4*)in + (size_t)i * 2;
  float4 a = p[0], b = p[1];
  bf16x8 o;
  o[0] = (short)f2bf(a.x); o[1] = (short)f2bf(a.y); o[2] = (short)f2bf(a.z); o[3] = (short)f2bf(a.w);
  o[4] = (short)f2bf(b.x); o[5] = (short)f2bf(b.y); o[6] = (short)f2bf(b.z); o[7] = (short)f2bf(b.w);
  *((bf16x8*)out + i) = o;
}

// ---------------- transpose + convert: W[K][N] f32 -> Wt[N][K] bf16 ----------------
__global__ __launch_bounds__(256) void k_transpose_bf16(const float* __restrict__ W,
                                                        bf16_t* __restrict__ Wt, int K, int N) {
  __shared__ bf16_t t[64][65];
  int n0 = blockIdx.x * 64, k0 = blockIdx.y * 64;
  int tid = threadIdx.x;
#pragma unroll
  for (int p = 0; p < 16; ++p) {
    int lin = p * 256 + tid;
    int r = lin >> 6, c = lin & 63;
    t[r][c] = f2bf(W[(size_t)(k0 + r) * N + n0 + c]);
  }
  __syncthreads();
#pragma unroll
  for (int p = 0; p < 16; ++p) {
    int lin = p * 256 + tid;
    int nr = lin >> 6, kc = lin & 63;
    Wt[(size_t)(n0 + nr) * K + k0 + kc] = t[kc][nr];
  }
}

// ---------------- GEMM-BT (m97 structure): C[M][N] = A[M][K] @ Bt[N][K]^T + bias ----------------
// SCALEQ: multiply cols < 1024 (the Q part of QKV) by 1/sqrt(64)*log2(e), folding the
// softmax scale into Q so k_attn skips the per-element multiply.
template <bool BF16OUT, bool SCALEQ>
__global__ __launch_bounds__(256) void k_gemm_bt(const bf16_t* __restrict__ A,
                                                 const bf16_t* __restrict__ Bt,
                                                 const float* __restrict__ bias,
                                                 void* __restrict__ Cout, int M, int N, int K) {
  __shared__ bf16_t Al[128 * 32];
  __shared__ bf16_t Bl[128 * 32];
  const int tid = threadIdx.x;
  const int lane = tid & 63;
  const int wid = tid >> 6;
  const int wm = wid >> 1, wn = wid & 1;
  const int m0 = blockIdx.y * 128, n0 = blockIdx.x * 128;
  const int lr = lane & 15;
  const int lk = lane >> 4;

  f32x4 acc[4][4] = {};

  for (int k0 = 0; k0 < K; k0 += 32) {
    __syncthreads();
#pragma unroll
    for (int p = 0; p < 2; ++p) {
      int o = p * 4096 + tid * 16;
      int row = o >> 6, cb = o & 63;
      gld_lds16((const char*)A + ((size_t)(m0 + row) * K + k0) * 2 + cb, (char*)Al + o);
      gld_lds16((const char*)Bt + ((size_t)(n0 + row) * K + k0) * 2 + cb, (char*)Bl + o);
    }
    __syncthreads();
    bf16x8 af[4], bfr[4];
#pragma unroll
    for (int i = 0; i < 4; ++i) {
      af[i]  = *(const bf16x8*)(Al + ((wm * 64 + i * 16 + lr) * 32 + lk * 8));
      bfr[i] = *(const bf16x8*)(Bl + ((wn * 64 + i * 16 + lr) * 32 + lk * 8));
    }
#pragma unroll
    for (int i = 0; i < 4; ++i)
#pragma unroll
      for (int j = 0; j < 4; ++j)
        acc[i][j] = MFMA16(af[i], bfr[j], acc[i][j]);
  }

#pragma unroll
  for (int i = 0; i < 4; ++i) {
    int grow = m0 + wm * 64 + i * 16 + lk * 4;
#pragma unroll
    for (int j = 0; j < 4; ++j) {
      int gcol = n0 + wn * 64 + j * 16 + lr;
      float bv = bias[gcol];
      float scl = (SCALEQ && gcol < 1024) ? 0.18033688011112042f : 1.0f;
#pragma unroll
      for (int r = 0; r < 4; ++r) {
        float v = (acc[i][j][r] + bv) * scl;
        size_t off = (size_t)(grow + r) * N + gcol;
        if (BF16OUT)
          ((bf16_t*)Cout)[off] = f2bf(v);
        else
          ((float*)Cout)[off] = v;
      }
    }
  }
}

// ---------------- fused causal attention (paired q-tiles, KVBLK=128) ----------------
// Grid: 512 blocks = 16 pairs x 32 (b,h). Block (pr,bh) runs q-tile pr then 31-pr
// (64 q-rows each; wave w owns rows [qt*64+w*16, +16)). kv-steps per pair:
// ((pr>>1)+1) + (((31-pr)>>1)+1) = 17 for every block -> perfectly balanced.
// Per step: issue current K-frag loads (global, L2-resident), barrier, write Vt
// from regs prefetched last step (conflict-free swizzle), prefetch next V, QK^T,
// online softmax (scale pre-folded into Q), P->LDS, barrier, PV.
// Raw s_barrier + lgkmcnt keeps vmem prefetch in flight across barriers.
__global__ __launch_bounds__(256) void k_attn(const bf16_t* __restrict__ qkv,
                                              bf16_t* __restrict__ score) {
  __shared__ bf16_t Vt[64 * 128];     // [d][kv] swizzled, 16 KiB
  __shared__ bf16_t Pl[4][16 * 128];  // per-wave P [q][kv] swizzled, 16 KiB
  const int tid = threadIdx.x;
  const int lane = tid & 63;
  const int w = tid >> 6;
  const int lr = lane & 15, lk = lane >> 4;

  const int flat = blockIdx.x;
  const int pr = flat >> 5;   // pair index 0..15
  const int bh = flat & 31;
  const int b = bh >> 4, h = bh & 15;

  const bf16_t* Qb = qkv + (size_t)b * 2048 * 3072 + h * 64;
  const bf16_t* Kb = Qb + 1024;
  const bf16_t* Vb = Qb + 2048;

  // V staging coords: pass p stages elems e=(p*256+tid)*8 of the [128kv][64d] tile
  int vkv[4], vd0[4];
#pragma unroll
  for (int p = 0; p < 4; ++p) {
    int e = (p * 256 + tid) * 8;
    vkv[p] = e >> 6;
    vd0[p] = e & 63;
  }

  for (int ph = 0; ph < 2; ++ph) {
    const int qt = ph ? (31 - pr) : pr;
    const int qr0 = qt * 64 + w * 16;
    const int jtEnd = (qt >> 1) + 1;

    // hoist Q fragments (pre-scaled by 1/sqrt(64)*log2e in the GEMM)
    bf16x8 qf[2];
#pragma unroll
    for (int ks = 0; ks < 2; ++ks)
      qf[ks] = *(const bf16x8*)(Qb + (size_t)(qr0 + lr) * 3072 + ks * 32 + lk * 8);

    f32x4 o[4] = {};
    float mm[4], ll[4];
#pragma unroll
    for (int r = 0; r < 4; ++r) { mm[r] = -INFINITY; ll[r] = 0.f; }

    // prologue: prefetch V tile 0 into regs
    bf16x8 vreg[4];
#pragma unroll
    for (int p = 0; p < 4; ++p)
      vreg[p] = *(const bf16x8*)(Vb + (size_t)vkv[p] * 3072 + vd0[p]);

    for (int jt = 0; jt < jtEnd; ++jt) {
      const int kv0 = jt * 128;
      const bool active = (kv0 <= qr0 + 15);

      // current-tile K fragments (global, L2-resident); issue before barrier so
      // latency hides under Vt writes
      bf16x8 kf[8][2];
      if (active) {
#pragma unroll
        for (int nc = 0; nc < 8; ++nc)
#pragma unroll
          for (int ks = 0; ks < 2; ++ks)
            kf[nc][ks] = *(const bf16x8*)(Kb + (size_t)(kv0 + nc * 16 + lr) * 3072 + ks * 32 + lk * 8);
      }
      // barrier1: all waves done reading Vt/Pl of previous step
      asm volatile("s_waitcnt lgkmcnt(0)" ::: "memory");
      __builtin_amdgcn_s_barrier();
      // write Vt from prefetched regs; swizzle nibble (d&7)^((d>>3)&7) spreads the
      // 8 lanes sharing kv across banks (write conflict-free), reads stay <=2-way
#pragma unroll
      for (int p = 0; p < 4; ++p)
#pragma unroll
        for (int j = 0; j < 8; ++j) {
          int d = vd0[p] + j;
          int addr = (d * 256 + vkv[p] * 2) ^ (((d & 7) ^ ((d >> 3) & 7)) << 4);
          *(bf16_t*)((char*)Vt + addr) = (bf16_t)vreg[p][j];
        }
      // prefetch next V tile (clamped; garbage unused on last step)
      const int kvn = (kv0 + 128 < 2048) ? kv0 + 128 : 1920;
      bf16x8 vregN[4];
#pragma unroll
      for (int p = 0; p < 4; ++p)
        vregN[p] = *(const bf16x8*)(Vb + (size_t)(kvn + vkv[p]) * 3072 + vd0[p]);

      if (active) {
        // S = Q K^T
        f32x4 s[8];
#pragma unroll
        for (int nc = 0; nc < 8; ++nc) {
          f32x4 z = {};
          z = MFMA16(qf[0], kf[nc][0], z);
          z = MFMA16(qf[1], kf[nc][1], z);
          s[nc] = z;
        }
        // causal mask (scale already folded into Q)
        if (kv0 + 127 > qr0) {
#pragma unroll
          for (int nc = 0; nc < 8; ++nc)
#pragma unroll
            for (int r = 0; r < 4; ++r) {
              int q = qr0 + lk * 4 + r;
              int kvi = kv0 + nc * 16 + lr;
              if (kvi > q) s[nc][r] = -INFINITY;
            }
        }
        // online softmax (base-2), reduce over the 16 lanes sharing lk
#pragma unroll
        for (int r = 0; r < 4; ++r) {
          float rm = s[0][r];
#pragma unroll
          for (int nc = 1; nc < 8; ++nc) rm = fmaxf(rm, s[nc][r]);
#pragma unroll
          for (int off = 1; off < 16; off <<= 1)
            rm = fmaxf(rm, __shfl_xor(rm, off, 16));
          float mnew = fmaxf(mm[r], rm);
          float alpha = exp2f(mm[r] - mnew);
          float ps = 0.f;
#pragma unroll
          for (int nc = 0; nc < 8; ++nc) {
            float pv = exp2f(s[nc][r] - mnew);
            s[nc][r] = pv;
            ps += pv;
          }
#pragma unroll
          for (int off = 1; off < 16; off <<= 1)
            ps += __shfl_xor(ps, off, 16);
          ll[r] = ll[r] * alpha + ps;
          mm[r] = mnew;
#pragma unroll
          for (int d = 0; d < 4; ++d) o[d][r] *= alpha;
        }
        // P -> per-wave LDS (bf16, swizzled)
        bf16_t* Pw = Pl[w];
#pragma unroll
        for (int nc = 0; nc < 8; ++nc)
#pragma unroll
          for (int r = 0; r < 4; ++r) {
            int row = lk * 4 + r;
            int col = nc * 16 + lr;
            int addr = (row * 256 + col * 2) ^ ((row & 7) << 4);
            *(bf16_t*)((char*)Pw + addr) = f2bf(s[nc][r]);
          }
      }
      // barrier2: Vt + P writes visible (lgkm only; vmem prefetch stays in flight)
      asm volatile("s_waitcnt lgkmcnt(0)" ::: "memory");
      __builtin_amdgcn_s_barrier();
      if (active) {
        bf16x8 pa[4];
#pragma unroll
        for (int ks = 0; ks < 4; ++ks) {
          int addr = (lr * 256 + ks * 64 + lk * 16) ^ ((lr & 7) << 4);
          pa[ks] = *(const bf16x8*)((const char*)Pl[w] + addr);
        }
#pragma unroll
        for (int db = 0; db < 4; ++db)
#pragma unroll
          for (int ks = 0; ks < 4; ++ks) {
            int d = db * 16 + lr;
            int addr = (d * 256 + ks * 64 + lk * 16) ^ (((d & 7) ^ ((d >> 3) & 7)) << 4);
            bf16x8 vb = *(const bf16x8*)((const char*)Vt + addr);
            o[db] = MFMA16(pa[ks], vb, o[db]);
          }
      }
      // rotate V prefetch
#pragma unroll
      for (int p = 0; p < 4; ++p) vreg[p] = vregN[p];
    }

    // epilogue for this phase
#pragma unroll
    for (int db = 0; db < 4; ++db)
#pragma unroll
      for (int r = 0; r < 4; ++r) {
        int qrow = qr0 + lk * 4 + r;
        float v = o[db][r] / ll[r];
        score[(size_t)(b * 2048 + qrow) * 1024 + h * 64 + db * 16 + lr] = f2bf(v);
      }
  }
}

extern "C" void kernel_launch(void* const* d_in, const int* in_sizes, int n_in,
                              void* d_out, int out_size, void* d_ws, size_t ws_size,
                              hipStream_t stream) {
  const float* X  = (const float*)d_in[0];  // [2,2048,1024]
  const float* Wa = (const float*)d_in[1];  // [1024,3072]
  const float* ba = (const float*)d_in[2];  // [3072]
  const float* Wp = (const float*)d_in[3];  // [1024,1024]
  const float* bp = (const float*)d_in[4];  // [1024]
  float* out = (float*)d_out;               // [2,2048,1024] fp32

  char* ws = (char*)d_ws;
  bf16_t* Xb  = (bf16_t*)ws;                          // 8 MiB (reused as score)
  bf16_t* WaT = (bf16_t*)(ws + (size_t)(8u << 20));   // 6 MiB: W_attn^T [3072][1024]
  bf16_t* WpT = (bf16_t*)(ws + (size_t)(14u << 20));  // 2 MiB: W_proj^T [1024][1024]
  bf16_t* QKV = (bf16_t*)(ws + (size_t)(16u << 20));  // 24 MiB: [4096][3072]
  bf16_t* S_  = Xb;

  k_f32_to_bf16<<<2048, 256, 0, stream>>>(X, Xb, 4096 * 1024 / 8);
  k_transpose_bf16<<<dim3(48, 16), 256, 0, stream>>>(Wa, WaT, 1024, 3072);
  k_transpose_bf16<<<dim3(16, 16), 256, 0, stream>>>(Wp, WpT, 1024, 1024);
  k_gemm_bt<true, true><<<dim3(24, 32), 256, 0, stream>>>(Xb, WaT, ba, QKV, 4096, 3072, 1024);
  k_attn<<<512, 256, 0, stream>>>(QKV, S_);
  k_gemm_bt<false, false><<<dim3(8, 32), 256, 0, stream>>>(S_, WpT, bp, out, 4096, 1024, 1024);
}

// Round 6
// 175.737 us; speedup vs baseline: 1.3043x; 1.3043x over previous
//
#include <hip/hip_runtime.h>
#include <hip/hip_bf16.h>

typedef unsigned short bf16_t;
typedef __attribute__((ext_vector_type(8))) short bf16x8;
typedef __attribute__((ext_vector_type(4))) float f32x4;

#define MFMA16(a, b, c) __builtin_amdgcn_mfma_f32_16x16x32_bf16((a), (b), (c), 0, 0, 0)

__device__ __forceinline__ bf16_t f2bf(float f) {
  union { float f; unsigned u; } v; v.f = f;
  unsigned u = v.u;
  u += 0x7FFFu + ((u >> 16) & 1u);
  return (bf16_t)(u >> 16);
}

__device__ __forceinline__ void gld_lds16(const void* g, void* l) {
  __builtin_amdgcn_global_load_lds(
      (const __attribute__((address_space(1))) unsigned int*)g,
      (__attribute__((address_space(3))) unsigned int*)l, 16, 0, 0);
}

// ---------------- elementwise fp32 -> bf16 (8/thread) ----------------
__global__ __launch_bounds__(256) void k_f32_to_bf16(const float* __restrict__ in,
                                                     bf16_t* __restrict__ out, int n8) {
  int i = blockIdx.x * 256 + threadIdx.x;
  if (i >= n8) return;
  const float4* p = (const float4*)in + (size_t)i * 2;
  float4 a = p[0], b = p[1];
  bf16x8 o;
  o[0] = (short)f2bf(a.x); o[1] = (short)f2bf(a.y); o[2] = (short)f2bf(a.z); o[3] = (short)f2bf(a.w);
  o[4] = (short)f2bf(b.x); o[5] = (short)f2bf(b.y); o[6] = (short)f2bf(b.z); o[7] = (short)f2bf(b.w);
  *((bf16x8*)out + i) = o;
}

// ---------------- transpose + convert: W[K][N] f32 -> Wt[N][K] bf16 ----------------
__global__ __launch_bounds__(256) void k_transpose_bf16(const float* __restrict__ W,
                                                        bf16_t* __restrict__ Wt, int K, int N) {
  __shared__ bf16_t t[64][65];
  int n0 = blockIdx.x * 64, k0 = blockIdx.y * 64;
  int tid = threadIdx.x;
#pragma unroll
  for (int p = 0; p < 16; ++p) {
    int lin = p * 256 + tid;
    int r = lin >> 6, c = lin & 63;
    t[r][c] = f2bf(W[(size_t)(k0 + r) * N + n0 + c]);
  }
  __syncthreads();
#pragma unroll
  for (int p = 0; p < 16; ++p) {
    int lin = p * 256 + tid;
    int nr = lin >> 6, kc = lin & 63;
    Wt[(size_t)(n0 + nr) * K + k0 + kc] = t[kc][nr];
  }
}

// ---------------- GEMM-BT (m97 structure): C[M][N] = A[M][K] @ Bt[N][K]^T + bias ----------------
// SCALEQ: multiply cols < 1024 (the Q part of QKV) by 1/sqrt(64)*log2(e), folding the
// softmax scale into Q so k_attn skips the per-element multiply.
template <bool BF16OUT, bool SCALEQ>
__global__ __launch_bounds__(256) void k_gemm_bt(const bf16_t* __restrict__ A,
                                                 const bf16_t* __restrict__ Bt,
                                                 const float* __restrict__ bias,
                                                 void* __restrict__ Cout, int M, int N, int K) {
  __shared__ bf16_t Al[128 * 32];
  __shared__ bf16_t Bl[128 * 32];
  const int tid = threadIdx.x;
  const int lane = tid & 63;
  const int wid = tid >> 6;
  const int wm = wid >> 1, wn = wid & 1;
  const int m0 = blockIdx.y * 128, n0 = blockIdx.x * 128;
  const int lr = lane & 15;
  const int lk = lane >> 4;

  f32x4 acc[4][4] = {};

  for (int k0 = 0; k0 < K; k0 += 32) {
    __syncthreads();
#pragma unroll
    for (int p = 0; p < 2; ++p) {
      int o = p * 4096 + tid * 16;
      int row = o >> 6, cb = o & 63;
      gld_lds16((const char*)A + ((size_t)(m0 + row) * K + k0) * 2 + cb, (char*)Al + o);
      gld_lds16((const char*)Bt + ((size_t)(n0 + row) * K + k0) * 2 + cb, (char*)Bl + o);
    }
    __syncthreads();
    bf16x8 af[4], bfr[4];
#pragma unroll
    for (int i = 0; i < 4; ++i) {
      af[i]  = *(const bf16x8*)(Al + ((wm * 64 + i * 16 + lr) * 32 + lk * 8));
      bfr[i] = *(const bf16x8*)(Bl + ((wn * 64 + i * 16 + lr) * 32 + lk * 8));
    }
#pragma unroll
    for (int i = 0; i < 4; ++i)
#pragma unroll
      for (int j = 0; j < 4; ++j)
        acc[i][j] = MFMA16(af[i], bfr[j], acc[i][j]);
  }

#pragma unroll
  for (int i = 0; i < 4; ++i) {
    int grow = m0 + wm * 64 + i * 16 + lk * 4;
#pragma unroll
    for (int j = 0; j < 4; ++j) {
      int gcol = n0 + wn * 64 + j * 16 + lr;
      float bv = bias[gcol];
      float scl = (SCALEQ && gcol < 1024) ? 0.18033688011112042f : 1.0f;
#pragma unroll
      for (int r = 0; r < 4; ++r) {
        float v = (acc[i][j][r] + bv) * scl;
        size_t off = (size_t)(grow + r) * N + gcol;
        if (BF16OUT)
          ((bf16_t*)Cout)[off] = f2bf(v);
        else
          ((float*)Cout)[off] = v;
      }
    }
  }
}

// ---------------- fused causal attention (paired q-tiles, KVBLK=64) ----------------
// R4-verified structure: 512 blocks = 16 pairs x 32 (b,h); block runs q-tile pr then
// 31-pr (64 q-rows each, wave w owns rows [qt*64+w*16,+16)); 33 kv-steps per block,
// perfectly balanced. K and V double-buffered in REGISTERS (prefetch one step ahead,
// VGPR ~104 -> 2 blocks/CU with full wave budget). Raw s_barrier + lgkmcnt keeps
// vmem prefetch in flight across barriers.
// R6 changes vs R4: (a) Vt swizzle nibble (d&7)^((d>>3)&7) on write+read — write-side
// conflict-free (R5-validated: conflicts 1.5e7 -> 2.8e6); (b) softmax scale folded
// into Q by the GEMM (SCALEQ), mask writes -INF directly.
__global__ __launch_bounds__(256) void k_attn(const bf16_t* __restrict__ qkv,
                                              bf16_t* __restrict__ score) {
  __shared__ bf16_t Vt[64 * 64];     // [d][kv] swizzled, 8 KiB
  __shared__ bf16_t Pl[4][16 * 64];  // per-wave P [q][kv] swizzled, 8 KiB
  const int tid = threadIdx.x;
  const int lane = tid & 63;
  const int w = tid >> 6;
  const int lr = lane & 15, lk = lane >> 4;

  const int flat = blockIdx.x;
  const int pr = flat >> 5;   // pair index 0..15
  const int bh = flat & 31;
  const int b = bh >> 4, h = bh & 15;

  const bf16_t* Qb = qkv + (size_t)b * 2048 * 3072 + h * 64;
  const bf16_t* Kb = Qb + 1024;
  const bf16_t* Vb = Qb + 2048;

  // V staging coords: pass p stages elems e=(p*256+tid)*8 of the [64kv][64d] tile
  int vkv[2], vd0[2];
#pragma unroll
  for (int p = 0; p < 2; ++p) {
    int e = (p * 256 + tid) * 8;
    vkv[p] = e >> 6;
    vd0[p] = e & 63;
  }

  for (int ph = 0; ph < 2; ++ph) {
    const int qt = ph ? (31 - pr) : pr;
    const int qr0 = qt * 64 + w * 16;
    const int jtEnd = qt + 1;

    // hoist Q fragments (pre-scaled by 1/sqrt(64)*log2e in the GEMM)
    bf16x8 qf[2];
#pragma unroll
    for (int ks = 0; ks < 2; ++ks)
      qf[ks] = *(const bf16x8*)(Qb + (size_t)(qr0 + lr) * 3072 + ks * 32 + lk * 8);

    f32x4 o[4] = {};
    float mm[4], ll[4];
#pragma unroll
    for (int r = 0; r < 4; ++r) { mm[r] = -INFINITY; ll[r] = 0.f; }

    // prologue: prefetch tile 0 into regs
    bf16x8 vreg[2], kf[4][2];
#pragma unroll
    for (int p = 0; p < 2; ++p)
      vreg[p] = *(const bf16x8*)(Vb + (size_t)vkv[p] * 3072 + vd0[p]);
#pragma unroll
    for (int nc = 0; nc < 4; ++nc)
#pragma unroll
      for (int ks = 0; ks < 2; ++ks)
        kf[nc][ks] = *(const bf16x8*)(Kb + (size_t)(nc * 16 + lr) * 3072 + ks * 32 + lk * 8);

    for (int jt = 0; jt < jtEnd; ++jt) {
      const int kv0 = jt * 64;
      // barrier1: all waves done reading Vt/Pl of previous step (lgkm only)
      asm volatile("s_waitcnt lgkmcnt(0)" ::: "memory");
      __builtin_amdgcn_s_barrier();
      // write Vt from prefetched regs; swizzle nibble (d&7)^((d>>3)&7):
      // per-instruction banks (kv>>1)^((j^(l&7))<<2) cover all 32 -> conflict-free
#pragma unroll
      for (int p = 0; p < 2; ++p)
#pragma unroll
        for (int j = 0; j < 8; ++j) {
          int d = vd0[p] + j;
          int addr = (d * 128 + vkv[p] * 2) ^ (((d & 7) ^ ((d >> 3) & 7)) << 4);
          *(bf16_t*)((char*)Vt + addr) = (bf16_t)vreg[p][j];
        }
      // prefetch next tile (clamped in-bounds; garbage unused on last step)
      const int kvn = (kv0 + 64 < 2048) ? (kv0 + 64) : 1984;
      bf16x8 vregN[2], kfN[4][2];
#pragma unroll
      for (int p = 0; p < 2; ++p)
        vregN[p] = *(const bf16x8*)(Vb + (size_t)(kvn + vkv[p]) * 3072 + vd0[p]);
#pragma unroll
      for (int nc = 0; nc < 4; ++nc)
#pragma unroll
        for (int ks = 0; ks < 2; ++ks)
          kfN[nc][ks] = *(const bf16x8*)(Kb + (size_t)(kvn + nc * 16 + lr) * 3072 + ks * 32 + lk * 8);

      const bool active = (kv0 <= qr0 + 15);
      if (active) {
        // S = Q K^T from register K-fragments (scale pre-folded into Q)
        f32x4 s[4];
#pragma unroll
        for (int nc = 0; nc < 4; ++nc) {
          f32x4 z = {};
          z = MFMA16(qf[0], kf[nc][0], z);
          z = MFMA16(qf[1], kf[nc][1], z);
          s[nc] = z;
        }
        // causal mask
        if (kv0 + 63 > qr0) {
#pragma unroll
          for (int nc = 0; nc < 4; ++nc)
#pragma unroll
            for (int r = 0; r < 4; ++r) {
              int q = qr0 + lk * 4 + r;
              int kvi = kv0 + nc * 16 + lr;
              if (kvi > q) s[nc][r] = -INFINITY;
            }
        }
        // online softmax (base-2), reduce over the 16 lanes sharing lk
#pragma unroll
        for (int r = 0; r < 4; ++r) {
          float rm = fmaxf(fmaxf(s[0][r], s[1][r]), fmaxf(s[2][r], s[3][r]));
#pragma unroll
          for (int off = 1; off < 16; off <<= 1)
            rm = fmaxf(rm, __shfl_xor(rm, off, 16));
          float mnew = fmaxf(mm[r], rm);
          float alpha = exp2f(mm[r] - mnew);
          float ps = 0.f;
#pragma unroll
          for (int nc = 0; nc < 4; ++nc) {
            float p = exp2f(s[nc][r] - mnew);
            s[nc][r] = p;
            ps += p;
          }
#pragma unroll
          for (int off = 1; off < 16; off <<= 1)
            ps += __shfl_xor(ps, off, 16);
          ll[r] = ll[r] * alpha + ps;
          mm[r] = mnew;
#pragma unroll
          for (int d = 0; d < 4; ++d) o[d][r] *= alpha;
        }
        // P -> per-wave LDS (bf16, swizzled)
        bf16_t* Pw = Pl[w];
#pragma unroll
        for (int nc = 0; nc < 4; ++nc)
#pragma unroll
          for (int r = 0; r < 4; ++r) {
            int row = lk * 4 + r;
            int col = nc * 16 + lr;
            int addr = (row * 128 + col * 2) ^ ((row & 7) << 4);
            *(bf16_t*)((char*)Pw + addr) = f2bf(s[nc][r]);
          }
      }
      // barrier2: Vt + P writes visible (lgkm only; vmem prefetch stays in flight)
      asm volatile("s_waitcnt lgkmcnt(0)" ::: "memory");
      __builtin_amdgcn_s_barrier();
      if (active) {
        bf16x8 pa[2];
#pragma unroll
        for (int ks = 0; ks < 2; ++ks) {
          int addr = (lr * 128 + ks * 64 + lk * 16) ^ ((lr & 7) << 4);
          pa[ks] = *(const bf16x8*)((const char*)Pl[w] + addr);
        }
#pragma unroll
        for (int db = 0; db < 4; ++db)
#pragma unroll
          for (int ks = 0; ks < 2; ++ks) {
            int d = db * 16 + lr;
            int addr = (d * 128 + ks * 64 + lk * 16) ^ (((d & 7) ^ ((d >> 3) & 7)) << 4);
            bf16x8 vb = *(const bf16x8*)((const char*)Vt + addr);
            o[db] = MFMA16(pa[ks], vb, o[db]);
          }
      }
      // rotate prefetch
#pragma unroll
      for (int p = 0; p < 2; ++p) vreg[p] = vregN[p];
#pragma unroll
      for (int nc = 0; nc < 4; ++nc)
#pragma unroll
        for (int ks = 0; ks < 2; ++ks) kf[nc][ks] = kfN[nc][ks];
    }

    // epilogue for this phase
#pragma unroll
    for (int db = 0; db < 4; ++db)
#pragma unroll
      for (int r = 0; r < 4; ++r) {
        int qrow = qr0 + lk * 4 + r;
        float v = o[db][r] / ll[r];
        score[(size_t)(b * 2048 + qrow) * 1024 + h * 64 + db * 16 + lr] = f2bf(v);
      }
  }
}

extern "C" void kernel_launch(void* const* d_in, const int* in_sizes, int n_in,
                              void* d_out, int out_size, void* d_ws, size_t ws_size,
                              hipStream_t stream) {
  const float* X  = (const float*)d_in[0];  // [2,2048,1024]
  const float* Wa = (const float*)d_in[1];  // [1024,3072]
  const float* ba = (const float*)d_in[2];  // [3072]
  const float* Wp = (const float*)d_in[3];  // [1024,1024]
  const float* bp = (const float*)d_in[4];  // [1024]
  float* out = (float*)d_out;               // [2,2048,1024] fp32

  char* ws = (char*)d_ws;
  bf16_t* Xb  = (bf16_t*)ws;                          // 8 MiB (reused as score)
  bf16_t* WaT = (bf16_t*)(ws + (size_t)(8u << 20));   // 6 MiB: W_attn^T [3072][1024]
  bf16_t* WpT = (bf16_t*)(ws + (size_t)(14u << 20));  // 2 MiB: W_proj^T [1024][1024]
  bf16_t* QKV = (bf16_t*)(ws + (size_t)(16u << 20));  // 24 MiB: [4096][3072]
  bf16_t* S_  = Xb;

  k_f32_to_bf16<<<2048, 256, 0, stream>>>(X, Xb, 4096 * 1024 / 8);
  k_transpose_bf16<<<dim3(48, 16), 256, 0, stream>>>(Wa, WaT, 1024, 3072);
  k_transpose_bf16<<<dim3(16, 16), 256, 0, stream>>>(Wp, WpT, 1024, 1024);
  k_gemm_bt<true, true><<<dim3(24, 32), 256, 0, stream>>>(Xb, WaT, ba, QKV, 4096, 3072, 1024);
  k_attn<<<512, 256, 0, stream>>>(QKV, S_);
  k_gemm_bt<false, false><<<dim3(8, 32), 256, 0, stream>>>(S_, WpT, bp, out, 4096, 1024, 1024);
}

// Round 7
// 158.431 us; speedup vs baseline: 1.4467x; 1.1092x over previous
//
#include <hip/hip_runtime.h>
#include <hip/hip_bf16.h>

typedef unsigned short bf16_t;
typedef __attribute__((ext_vector_type(8))) short bf16x8;
typedef __attribute__((ext_vector_type(4))) float f32x4;

#define MFMA16(a, b, c) __builtin_amdgcn_mfma_f32_16x16x32_bf16((a), (b), (c), 0, 0, 0)

__device__ __forceinline__ bf16_t f2bf(float f) {
  union { float f; unsigned u; } v; v.f = f;
  unsigned u = v.u;
  u += 0x7FFFu + ((u >> 16) & 1u);
  return (bf16_t)(u >> 16);
}

__device__ __forceinline__ void gld_lds16(const void* g, void* l) {
  __builtin_amdgcn_global_load_lds(
      (const __attribute__((address_space(1))) unsigned int*)g,
      (__attribute__((address_space(3))) unsigned int*)l, 16, 0, 0);
}

// ---- DPP 16-lane butterfly reduction (VALU-only; replaces ds_bpermute shuffles) ----
// steps: quad_perm xor1 (0xB1), quad_perm xor2 (0x4E), row_half_mirror (0x141, i^7),
// row_mirror (0x140, i^15) — each an involutive pairing across complementary groups,
// so the butterfly yields the full 16-lane reduction for max and sum.
template <int CTRL>
__device__ __forceinline__ float dppf(float v) {
  int i = __builtin_bit_cast(int, v);
  int r = __builtin_amdgcn_update_dpp(i, i, CTRL, 0xF, 0xF, true);
  return __builtin_bit_cast(float, r);
}
__device__ __forceinline__ float red16_max(float v) {
  v = fmaxf(v, dppf<0xB1>(v));
  v = fmaxf(v, dppf<0x4E>(v));
  v = fmaxf(v, dppf<0x141>(v));
  v = fmaxf(v, dppf<0x140>(v));
  return v;
}
__device__ __forceinline__ float red16_sum(float v) {
  v += dppf<0xB1>(v);
  v += dppf<0x4E>(v);
  v += dppf<0x141>(v);
  v += dppf<0x140>(v);
  return v;
}

// ---------------- elementwise fp32 -> bf16 (8/thread) ----------------
__global__ __launch_bounds__(256) void k_f32_to_bf16(const float* __restrict__ in,
                                                     bf16_t* __restrict__ out, int n8) {
  int i = blockIdx.x * 256 + threadIdx.x;
  if (i >= n8) return;
  const float4* p = (const float4*)in + (size_t)i * 2;
  float4 a = p[0], b = p[1];
  bf16x8 o;
  o[0] = (short)f2bf(a.x); o[1] = (short)f2bf(a.y); o[2] = (short)f2bf(a.z); o[3] = (short)f2bf(a.w);
  o[4] = (short)f2bf(b.x); o[5] = (short)f2bf(b.y); o[6] = (short)f2bf(b.z); o[7] = (short)f2bf(b.w);
  *((bf16x8*)out + i) = o;
}

// ---------------- transpose + convert: W[K][N] f32 -> Wt[N][K] bf16 ----------------
__global__ __launch_bounds__(256) void k_transpose_bf16(const float* __restrict__ W,
                                                        bf16_t* __restrict__ Wt, int K, int N) {
  __shared__ bf16_t t[64][65];
  int n0 = blockIdx.x * 64, k0 = blockIdx.y * 64;
  int tid = threadIdx.x;
#pragma unroll
  for (int p = 0; p < 16; ++p) {
    int lin = p * 256 + tid;
    int r = lin >> 6, c = lin & 63;
    t[r][c] = f2bf(W[(size_t)(k0 + r) * N + n0 + c]);
  }
  __syncthreads();
#pragma unroll
  for (int p = 0; p < 16; ++p) {
    int lin = p * 256 + tid;
    int nr = lin >> 6, kc = lin & 63;
    Wt[(size_t)(n0 + nr) * K + k0 + kc] = t[kc][nr];
  }
}

// ---------------- GEMM-BT (m97 structure): C[M][N] = A[M][K] @ Bt[N][K]^T + bias ----------------
// SCALEQ: multiply cols < 1024 (the Q part of QKV) by 1/sqrt(64)*log2(e), folding the
// softmax scale into Q so k_attn skips the per-element multiply.
template <bool BF16OUT, bool SCALEQ>
__global__ __launch_bounds__(256) void k_gemm_bt(const bf16_t* __restrict__ A,
                                                 const bf16_t* __restrict__ Bt,
                                                 const float* __restrict__ bias,
                                                 void* __restrict__ Cout, int M, int N, int K) {
  __shared__ bf16_t Al[128 * 32];
  __shared__ bf16_t Bl[128 * 32];
  const int tid = threadIdx.x;
  const int lane = tid & 63;
  const int wid = tid >> 6;
  const int wm = wid >> 1, wn = wid & 1;
  const int m0 = blockIdx.y * 128, n0 = blockIdx.x * 128;
  const int lr = lane & 15;
  const int lk = lane >> 4;

  f32x4 acc[4][4] = {};

  for (int k0 = 0; k0 < K; k0 += 32) {
    __syncthreads();
#pragma unroll
    for (int p = 0; p < 2; ++p) {
      int o = p * 4096 + tid * 16;
      int row = o >> 6, cb = o & 63;
      gld_lds16((const char*)A + ((size_t)(m0 + row) * K + k0) * 2 + cb, (char*)Al + o);
      gld_lds16((const char*)Bt + ((size_t)(n0 + row) * K + k0) * 2 + cb, (char*)Bl + o);
    }
    __syncthreads();
    bf16x8 af[4], bfr[4];
#pragma unroll
    for (int i = 0; i < 4; ++i) {
      af[i]  = *(const bf16x8*)(Al + ((wm * 64 + i * 16 + lr) * 32 + lk * 8));
      bfr[i] = *(const bf16x8*)(Bl + ((wn * 64 + i * 16 + lr) * 32 + lk * 8));
    }
#pragma unroll
    for (int i = 0; i < 4; ++i)
#pragma unroll
      for (int j = 0; j < 4; ++j)
        acc[i][j] = MFMA16(af[i], bfr[j], acc[i][j]);
  }

#pragma unroll
  for (int i = 0; i < 4; ++i) {
    int grow = m0 + wm * 64 + i * 16 + lk * 4;
#pragma unroll
    for (int j = 0; j < 4; ++j) {
      int gcol = n0 + wn * 64 + j * 16 + lr;
      float bv = bias[gcol];
      float scl = (SCALEQ && gcol < 1024) ? 0.18033688011112042f : 1.0f;
#pragma unroll
      for (int r = 0; r < 4; ++r) {
        float v = (acc[i][j][r] + bv) * scl;
        size_t off = (size_t)(grow + r) * N + gcol;
        if (BF16OUT)
          ((bf16_t*)Cout)[off] = f2bf(v);
        else
          ((float*)Cout)[off] = v;
      }
    }
  }
}

// ---------------- fused causal attention (paired q-tiles, KVBLK=64) ----------------
// R6-verified structure: 512 blocks = 16 pairs x 32 (b,h); block runs q-tile pr then
// 31-pr (64 q-rows each, wave w owns rows [qt*64+w*16,+16)); 33 kv-steps per block,
// perfectly balanced. K and V double-buffered in registers; raw s_barrier + lgkmcnt
// keeps vmem prefetch in flight. Vt swizzle (d&7)^((d>>3)&7) (R6-verified).
// R7 changes: (a) softmax sum-reduce deferred to epilogue (ll = per-lane partial;
// alpha is lane-uniform so partials scale consistently); (b) max-reduce via DPP
// butterfly (VALU) instead of __shfl_xor/ds_bpermute; (c) s_setprio around MFMAs.
__global__ __launch_bounds__(256) void k_attn(const bf16_t* __restrict__ qkv,
                                              bf16_t* __restrict__ score) {
  __shared__ bf16_t Vt[64 * 64];     // [d][kv] swizzled, 8 KiB
  __shared__ bf16_t Pl[4][16 * 64];  // per-wave P [q][kv] swizzled, 8 KiB
  const int tid = threadIdx.x;
  const int lane = tid & 63;
  const int w = tid >> 6;
  const int lr = lane & 15, lk = lane >> 4;

  const int flat = blockIdx.x;
  const int pr = flat >> 5;   // pair index 0..15
  const int bh = flat & 31;
  const int b = bh >> 4, h = bh & 15;

  const bf16_t* Qb = qkv + (size_t)b * 2048 * 3072 + h * 64;
  const bf16_t* Kb = Qb + 1024;
  const bf16_t* Vb = Qb + 2048;

  // V staging coords: pass p stages elems e=(p*256+tid)*8 of the [64kv][64d] tile
  int vkv[2], vd0[2];
#pragma unroll
  for (int p = 0; p < 2; ++p) {
    int e = (p * 256 + tid) * 8;
    vkv[p] = e >> 6;
    vd0[p] = e & 63;
  }

  for (int ph = 0; ph < 2; ++ph) {
    const int qt = ph ? (31 - pr) : pr;
    const int qr0 = qt * 64 + w * 16;
    const int jtEnd = qt + 1;

    // hoist Q fragments (pre-scaled by 1/sqrt(64)*log2e in the GEMM)
    bf16x8 qf[2];
#pragma unroll
    for (int ks = 0; ks < 2; ++ks)
      qf[ks] = *(const bf16x8*)(Qb + (size_t)(qr0 + lr) * 3072 + ks * 32 + lk * 8);

    f32x4 o[4] = {};
    float mm[4], ll[4];
#pragma unroll
    for (int r = 0; r < 4; ++r) { mm[r] = -INFINITY; ll[r] = 0.f; }

    // prologue: prefetch tile 0 into regs
    bf16x8 vreg[2], kf[4][2];
#pragma unroll
    for (int p = 0; p < 2; ++p)
      vreg[p] = *(const bf16x8*)(Vb + (size_t)vkv[p] * 3072 + vd0[p]);
#pragma unroll
    for (int nc = 0; nc < 4; ++nc)
#pragma unroll
      for (int ks = 0; ks < 2; ++ks)
        kf[nc][ks] = *(const bf16x8*)(Kb + (size_t)(nc * 16 + lr) * 3072 + ks * 32 + lk * 8);

    for (int jt = 0; jt < jtEnd; ++jt) {
      const int kv0 = jt * 64;
      // barrier1: all waves done reading Vt/Pl of previous step (lgkm only)
      asm volatile("s_waitcnt lgkmcnt(0)" ::: "memory");
      __builtin_amdgcn_s_barrier();
      // write Vt from prefetched regs (conflict-free swizzle, R6-verified)
#pragma unroll
      for (int p = 0; p < 2; ++p)
#pragma unroll
        for (int j = 0; j < 8; ++j) {
          int d = vd0[p] + j;
          int addr = (d * 128 + vkv[p] * 2) ^ (((d & 7) ^ ((d >> 3) & 7)) << 4);
          *(bf16_t*)((char*)Vt + addr) = (bf16_t)vreg[p][j];
        }
      // prefetch next tile (clamped in-bounds; garbage unused on last step)
      const int kvn = (kv0 + 64 < 2048) ? (kv0 + 64) : 1984;
      bf16x8 vregN[2], kfN[4][2];
#pragma unroll
      for (int p = 0; p < 2; ++p)
        vregN[p] = *(const bf16x8*)(Vb + (size_t)(kvn + vkv[p]) * 3072 + vd0[p]);
#pragma unroll
      for (int nc = 0; nc < 4; ++nc)
#pragma unroll
        for (int ks = 0; ks < 2; ++ks)
          kfN[nc][ks] = *(const bf16x8*)(Kb + (size_t)(kvn + nc * 16 + lr) * 3072 + ks * 32 + lk * 8);

      const bool active = (kv0 <= qr0 + 15);
      if (active) {
        // S = Q K^T from register K-fragments (scale pre-folded into Q)
        f32x4 s[4];
        __builtin_amdgcn_s_setprio(1);
#pragma unroll
        for (int nc = 0; nc < 4; ++nc) {
          f32x4 z = {};
          z = MFMA16(qf[0], kf[nc][0], z);
          z = MFMA16(qf[1], kf[nc][1], z);
          s[nc] = z;
        }
        __builtin_amdgcn_s_setprio(0);
        // causal mask
        if (kv0 + 63 > qr0) {
#pragma unroll
          for (int nc = 0; nc < 4; ++nc)
#pragma unroll
            for (int r = 0; r < 4; ++r) {
              int q = qr0 + lk * 4 + r;
              int kvi = kv0 + nc * 16 + lr;
              if (kvi > q) s[nc][r] = -INFINITY;
            }
        }
        // online softmax (base-2): DPP max-reduce; sum kept as PER-LANE partial
        // (alpha is uniform across the 16-lane group, so partials stay consistent;
        // the 16-lane sum happens once in the epilogue)
#pragma unroll
        for (int r = 0; r < 4; ++r) {
          float rm = fmaxf(fmaxf(s[0][r], s[1][r]), fmaxf(s[2][r], s[3][r]));
          rm = red16_max(rm);
          float mnew = fmaxf(mm[r], rm);
          float alpha = exp2f(mm[r] - mnew);
          float ps = 0.f;
#pragma unroll
          for (int nc = 0; nc < 4; ++nc) {
            float p = exp2f(s[nc][r] - mnew);
            s[nc][r] = p;
            ps += p;
          }
          ll[r] = ll[r] * alpha + ps;
          mm[r] = mnew;
#pragma unroll
          for (int d = 0; d < 4; ++d) o[d][r] *= alpha;
        }
        // P -> per-wave LDS (bf16, swizzled)
        bf16_t* Pw = Pl[w];
#pragma unroll
        for (int nc = 0; nc < 4; ++nc)
#pragma unroll
          for (int r = 0; r < 4; ++r) {
            int row = lk * 4 + r;
            int col = nc * 16 + lr;
            int addr = (row * 128 + col * 2) ^ ((row & 7) << 4);
            *(bf16_t*)((char*)Pw + addr) = f2bf(s[nc][r]);
          }
      }
      // barrier2: Vt + P writes visible (lgkm only; vmem prefetch stays in flight)
      asm volatile("s_waitcnt lgkmcnt(0)" ::: "memory");
      __builtin_amdgcn_s_barrier();
      if (active) {
        bf16x8 pa[2];
#pragma unroll
        for (int ks = 0; ks < 2; ++ks) {
          int addr = (lr * 128 + ks * 64 + lk * 16) ^ ((lr & 7) << 4);
          pa[ks] = *(const bf16x8*)((const char*)Pl[w] + addr);
        }
        __builtin_amdgcn_s_setprio(1);
#pragma unroll
        for (int db = 0; db < 4; ++db)
#pragma unroll
          for (int ks = 0; ks < 2; ++ks) {
            int d = db * 16 + lr;
            int addr = (d * 128 + ks * 64 + lk * 16) ^ (((d & 7) ^ ((d >> 3) & 7)) << 4);
            bf16x8 vb = *(const bf16x8*)((const char*)Vt + addr);
            o[db] = MFMA16(pa[ks], vb, o[db]);
          }
        __builtin_amdgcn_s_setprio(0);
      }
      // rotate prefetch
#pragma unroll
      for (int p = 0; p < 2; ++p) vreg[p] = vregN[p];
#pragma unroll
      for (int nc = 0; nc < 4; ++nc)
#pragma unroll
        for (int ks = 0; ks < 2; ++ks) kf[nc][ks] = kfN[nc][ks];
    }

    // epilogue for this phase: finish the deferred 16-lane sum of ll, then divide
#pragma unroll
    for (int r = 0; r < 4; ++r) ll[r] = red16_sum(ll[r]);
#pragma unroll
    for (int db = 0; db < 4; ++db)
#pragma unroll
      for (int r = 0; r < 4; ++r) {
        int qrow = qr0 + lk * 4 + r;
        float v = o[db][r] / ll[r];
        score[(size_t)(b * 2048 + qrow) * 1024 + h * 64 + db * 16 + lr] = f2bf(v);
      }
  }
}

extern "C" void kernel_launch(void* const* d_in, const int* in_sizes, int n_in,
                              void* d_out, int out_size, void* d_ws, size_t ws_size,
                              hipStream_t stream) {
  const float* X  = (const float*)d_in[0];  // [2,2048,1024]
  const float* Wa = (const float*)d_in[1];  // [1024,3072]
  const float* ba = (const float*)d_in[2];  // [3072]
  const float* Wp = (const float*)d_in[3];  // [1024,1024]
  const float* bp = (const float*)d_in[4];  // [1024]
  float* out = (float*)d_out;               // [2,2048,1024] fp32

  char* ws = (char*)d_ws;
  bf16_t* Xb  = (bf16_t*)ws;                          // 8 MiB (reused as score)
  bf16_t* WaT = (bf16_t*)(ws + (size_t)(8u << 20));   // 6 MiB: W_attn^T [3072][1024]
  bf16_t* WpT = (bf16_t*)(ws + (size_t)(14u << 20));  // 2 MiB: W_proj^T [1024][1024]
  bf16_t* QKV = (bf16_t*)(ws + (size_t)(16u << 20));  // 24 MiB: [4096][3072]
  bf16_t* S_  = Xb;

  k_f32_to_bf16<<<2048, 256, 0, stream>>>(X, Xb, 4096 * 1024 / 8);
  k_transpose_bf16<<<dim3(48, 16), 256, 0, stream>>>(Wa, WaT, 1024, 3072);
  k_transpose_bf16<<<dim3(16, 16), 256, 0, stream>>>(Wp, WpT, 1024, 1024);
  k_gemm_bt<true, true><<<dim3(24, 32), 256, 0, stream>>>(Xb, WaT, ba, QKV, 4096, 3072, 1024);
  k_attn<<<512, 256, 0, stream>>>(QKV, S_);
  k_gemm_bt<false, false><<<dim3(8, 32), 256, 0, stream>>>(S_, WpT, bp, out, 4096, 1024, 1024);
}

// Round 8
// 156.564 us; speedup vs baseline: 1.4640x; 1.0119x over previous
//
#include <hip/hip_runtime.h>
#include <hip/hip_bf16.h>

typedef unsigned short bf16_t;
typedef __attribute__((ext_vector_type(8))) short bf16x8;
typedef __attribute__((ext_vector_type(4))) float f32x4;

#define MFMA16(a, b, c) __builtin_amdgcn_mfma_f32_16x16x32_bf16((a), (b), (c), 0, 0, 0)

__device__ __forceinline__ bf16_t f2bf(float f) {
  union { float f; unsigned u; } v; v.f = f;
  unsigned u = v.u;
  u += 0x7FFFu + ((u >> 16) & 1u);
  return (bf16_t)(u >> 16);
}

__device__ __forceinline__ void gld_lds16(const void* g, void* l) {
  __builtin_amdgcn_global_load_lds(
      (const __attribute__((address_space(1))) unsigned int*)g,
      (__attribute__((address_space(3))) unsigned int*)l, 16, 0, 0);
}

// ---- DPP 16-lane butterfly reduction (VALU-only) ----
template <int CTRL>
__device__ __forceinline__ float dppf(float v) {
  int i = __builtin_bit_cast(int, v);
  int r = __builtin_amdgcn_update_dpp(i, i, CTRL, 0xF, 0xF, true);
  return __builtin_bit_cast(float, r);
}
__device__ __forceinline__ float red16_max(float v) {
  v = fmaxf(v, dppf<0xB1>(v));
  v = fmaxf(v, dppf<0x4E>(v));
  v = fmaxf(v, dppf<0x141>(v));
  v = fmaxf(v, dppf<0x140>(v));
  return v;
}
__device__ __forceinline__ float red16_sum(float v) {
  v += dppf<0xB1>(v);
  v += dppf<0x4E>(v);
  v += dppf<0x141>(v);
  v += dppf<0x140>(v);
  return v;
}

// ---------------- elementwise fp32 -> bf16 (8/thread) ----------------
__global__ __launch_bounds__(256) void k_f32_to_bf16(const float* __restrict__ in,
                                                     bf16_t* __restrict__ out, int n8) {
  int i = blockIdx.x * 256 + threadIdx.x;
  if (i >= n8) return;
  const float4* p = (const float4*)in + (size_t)i * 2;
  float4 a = p[0], b = p[1];
  bf16x8 o;
  o[0] = (short)f2bf(a.x); o[1] = (short)f2bf(a.y); o[2] = (short)f2bf(a.z); o[3] = (short)f2bf(a.w);
  o[4] = (short)f2bf(b.x); o[5] = (short)f2bf(b.y); o[6] = (short)f2bf(b.z); o[7] = (short)f2bf(b.w);
  *((bf16x8*)out + i) = o;
}

// ---------------- transpose + convert: W[K][N] f32 -> Wt[N][K] bf16 ----------------
__global__ __launch_bounds__(256) void k_transpose_bf16(const float* __restrict__ W,
                                                        bf16_t* __restrict__ Wt, int K, int N) {
  __shared__ bf16_t t[64][65];
  int n0 = blockIdx.x * 64, k0 = blockIdx.y * 64;
  int tid = threadIdx.x;
#pragma unroll
  for (int p = 0; p < 16; ++p) {
    int lin = p * 256 + tid;
    int r = lin >> 6, c = lin & 63;
    t[r][c] = f2bf(W[(size_t)(k0 + r) * N + n0 + c]);
  }
  __syncthreads();
#pragma unroll
  for (int p = 0; p < 16; ++p) {
    int lin = p * 256 + tid;
    int nr = lin >> 6, kc = lin & 63;
    Wt[(size_t)(n0 + nr) * K + k0 + kc] = t[kc][nr];
  }
}

// ---------------- GEMM-BT (m97 structure) with 1-D grid + XCD swizzle ----------------
// C[M][N] = A[M][K] @ Bt[N][K]^T + bias. grid = (M/128)*(N/128) blocks, % 8 == 0.
// SCALEQ folds 1/sqrt(64)*log2(e) into the Q columns (< 1024) of the QKV output.
template <bool BF16OUT, bool SCALEQ>
__global__ __launch_bounds__(256) void k_gemm_bt(const bf16_t* __restrict__ A,
                                                 const bf16_t* __restrict__ Bt,
                                                 const float* __restrict__ bias,
                                                 void* __restrict__ Cout, int M, int N, int K,
                                                 int nx) {
  __shared__ bf16_t Al[128 * 32];
  __shared__ bf16_t Bl[128 * 32];
  const int tid = threadIdx.x;
  const int lane = tid & 63;
  const int wid = tid >> 6;
  const int wm = wid >> 1, wn = wid & 1;
  // bijective XCD swizzle (gridDim.x % 8 == 0): each XCD gets a contiguous chunk
  const int nwg = gridDim.x;
  const int cpx = nwg >> 3;
  const int swz = (blockIdx.x & 7) * cpx + (blockIdx.x >> 3);
  const int m0 = (swz / nx) * 128, n0 = (swz % nx) * 128;
  const int lr = lane & 15;
  const int lk = lane >> 4;

  f32x4 acc[4][4] = {};

  for (int k0 = 0; k0 < K; k0 += 32) {
    __syncthreads();
#pragma unroll
    for (int p = 0; p < 2; ++p) {
      int o = p * 4096 + tid * 16;
      int row = o >> 6, cb = o & 63;
      gld_lds16((const char*)A + ((size_t)(m0 + row) * K + k0) * 2 + cb, (char*)Al + o);
      gld_lds16((const char*)Bt + ((size_t)(n0 + row) * K + k0) * 2 + cb, (char*)Bl + o);
    }
    __syncthreads();
    bf16x8 af[4], bfr[4];
#pragma unroll
    for (int i = 0; i < 4; ++i) {
      af[i]  = *(const bf16x8*)(Al + ((wm * 64 + i * 16 + lr) * 32 + lk * 8));
      bfr[i] = *(const bf16x8*)(Bl + ((wn * 64 + i * 16 + lr) * 32 + lk * 8));
    }
#pragma unroll
    for (int i = 0; i < 4; ++i)
#pragma unroll
      for (int j = 0; j < 4; ++j)
        acc[i][j] = MFMA16(af[i], bfr[j], acc[i][j]);
  }

#pragma unroll
  for (int i = 0; i < 4; ++i) {
    int grow = m0 + wm * 64 + i * 16 + lk * 4;
#pragma unroll
    for (int j = 0; j < 4; ++j) {
      int gcol = n0 + wn * 64 + j * 16 + lr;
      float bv = bias[gcol];
      float scl = (SCALEQ && gcol < 1024) ? 0.18033688011112042f : 1.0f;
#pragma unroll
      for (int r = 0; r < 4; ++r) {
        float v = (acc[i][j][r] + bv) * scl;
        size_t off = (size_t)(grow + r) * N + gcol;
        if (BF16OUT)
          ((bf16_t*)Cout)[off] = f2bf(v);
        else
          ((float*)Cout)[off] = v;
      }
    }
  }
}

// ---------------- fused causal attention (paired q-tiles, KVBLK=64) ----------------
// R7-verified structure: 512 blocks = 16 pairs x 32 (b,h); block runs q-tile pr then
// 31-pr (64 q-rows; wave w owns rows [qt*64+w*16,+16)); 33 steps/block, balanced.
// R8: (a) Vt double-buffered -> ONE barrier/step (write V(jt+1) to buf[(jt+1)&1]
// after the barrier; PV reads buf[jt&1]; lgkm-drain before barrier makes this safe;
// Pl is wave-private, needs no barrier); (b) ping-pong prefetch regs (no rotate
// movs), prefetch issued after QK^T so kfC/kfN lifetimes don't overlap; (c) T13
// defer-rescale: skip alpha path when no row max grew (wave-uniform __any).
__global__ __launch_bounds__(256) void k_attn(const bf16_t* __restrict__ qkv,
                                              bf16_t* __restrict__ score) {
  __shared__ bf16_t Vt[2][64 * 64];  // [buf][d][kv] swizzled, 16 KiB
  __shared__ bf16_t Pl[4][16 * 64];  // per-wave P [q][kv] swizzled, 8 KiB
  const int tid = threadIdx.x;
  const int lane = tid & 63;
  const int w = tid >> 6;
  const int lr = lane & 15, lk = lane >> 4;

  const int flat = blockIdx.x;
  const int pr = flat >> 5;  // pair index 0..15
  const int bh = flat & 31;
  const int b = bh >> 4, h = bh & 15;

  const bf16_t* Qb = qkv + (size_t)b * 2048 * 3072 + h * 64;
  const bf16_t* Kb = Qb + 1024;
  const bf16_t* Vb = Qb + 2048;

  // V staging coords: pass p handles elems e=(p*256+tid)*8 of the [64kv][64d] tile
  int vkv[2], vd0[2];
#pragma unroll
  for (int p = 0; p < 2; ++p) {
    int e = (p * 256 + tid) * 8;
    vkv[p] = e >> 6;
    vd0[p] = e & 63;
  }

  for (int ph = 0; ph < 2; ++ph) {
    const int qt = ph ? (31 - pr) : pr;
    const int qr0 = qt * 64 + w * 16;
    const int jtEnd = qt + 1;

    // hoist Q fragments (pre-scaled by 1/sqrt(64)*log2e in the GEMM)
    bf16x8 qf[2];
#pragma unroll
    for (int ks = 0; ks < 2; ++ks)
      qf[ks] = *(const bf16x8*)(Qb + (size_t)(qr0 + lr) * 3072 + ks * 32 + lk * 8);

    f32x4 o[4] = {};
    float mm[4], ll[4];
#pragma unroll
    for (int r = 0; r < 4; ++r) { mm[r] = -INFINITY; ll[r] = 0.f; }

    // phase prologue: V(0) -> buf0 (barrier first: prior phase's reads must drain)
    {
      bf16x8 v0[2];
#pragma unroll
      for (int p = 0; p < 2; ++p)
        v0[p] = *(const bf16x8*)(Vb + (size_t)vkv[p] * 3072 + vd0[p]);
      asm volatile("s_waitcnt lgkmcnt(0)" ::: "memory");
      __builtin_amdgcn_s_barrier();
#pragma unroll
      for (int p = 0; p < 2; ++p)
#pragma unroll
        for (int j = 0; j < 8; ++j) {
          int d = vd0[p] + j;
          int addr = (d * 128 + vkv[p] * 2) ^ (((d & 7) ^ ((d >> 3) & 7)) << 4);
          *(bf16_t*)((char*)Vt + addr) = (bf16_t)v0[p][j];
        }
    }
    // prefetch V(1) and K(0)
    bf16x8 vrA[2], vrB[2], kfA[4][2], kfB[4][2];
#pragma unroll
    for (int p = 0; p < 2; ++p)
      vrA[p] = *(const bf16x8*)(Vb + (size_t)(64 + vkv[p]) * 3072 + vd0[p]);
#pragma unroll
    for (int nc = 0; nc < 4; ++nc)
#pragma unroll
      for (int ks = 0; ks < 2; ++ks)
        kfA[nc][ks] = *(const bf16x8*)(Kb + (size_t)(nc * 16 + lr) * 3072 + ks * 32 + lk * 8);

    auto STEP = [&](int jt, bf16x8 (&vrC)[2], bf16x8 (&kfC)[4][2],
                    bf16x8 (&vrN)[2], bf16x8 (&kfN)[4][2]) {
      const int kv0 = jt * 64;
      // one barrier/step: prev-step Vt writes visible; all waves' prev reads drained
      asm volatile("s_waitcnt lgkmcnt(0)" ::: "memory");
      __builtin_amdgcn_s_barrier();
      // write V(jt+1) from regs into buf[(jt+1)&1] (conflict-free swizzle)
      char* wbase = (char*)Vt + (((jt + 1) & 1) << 13);
#pragma unroll
      for (int p = 0; p < 2; ++p)
#pragma unroll
        for (int j = 0; j < 8; ++j) {
          int d = vd0[p] + j;
          int addr = (d * 128 + vkv[p] * 2) ^ (((d & 7) ^ ((d >> 3) & 7)) << 4);
          *(bf16_t*)(wbase + addr) = (bf16_t)vrC[p][j];
        }
      // S = Q K^T from register K-fragments
      f32x4 s[4];
      __builtin_amdgcn_s_setprio(1);
#pragma unroll
      for (int nc = 0; nc < 4; ++nc) {
        f32x4 z = {};
        z = MFMA16(qf[0], kfC[nc][0], z);
        z = MFMA16(qf[1], kfC[nc][1], z);
        s[nc] = z;
      }
      __builtin_amdgcn_s_setprio(0);
      // prefetch K(jt+1), V(jt+2) — after kfC's last use (register reuse), in
      // flight through softmax/PV/next barrier (clamped; garbage unused at end)
      const int kvK = (kv0 + 64 < 2048) ? kv0 + 64 : 1984;
      const int kvV = (kv0 + 128 < 2048) ? kv0 + 128 : 1984;
#pragma unroll
      for (int nc = 0; nc < 4; ++nc)
#pragma unroll
        for (int ks = 0; ks < 2; ++ks)
          kfN[nc][ks] = *(const bf16x8*)(Kb + (size_t)(kvK + nc * 16 + lr) * 3072 + ks * 32 + lk * 8);
#pragma unroll
      for (int p = 0; p < 2; ++p)
        vrN[p] = *(const bf16x8*)(Vb + (size_t)(kvV + vkv[p]) * 3072 + vd0[p]);
      // causal mask (last tile of this wave only)
      if (kv0 + 63 > qr0) {
#pragma unroll
        for (int nc = 0; nc < 4; ++nc)
#pragma unroll
          for (int r = 0; r < 4; ++r) {
            int q = qr0 + lk * 4 + r;
            int kvi = kv0 + nc * 16 + lr;
            if (kvi > q) s[nc][r] = -INFINITY;
          }
      }
      // online softmax (base-2), DPP max-reduce, T13 defer-rescale
      float rm[4];
#pragma unroll
      for (int r = 0; r < 4; ++r)
        rm[r] = red16_max(fmaxf(fmaxf(s[0][r], s[1][r]), fmaxf(s[2][r], s[3][r])));
      bool grow = (rm[0] > mm[0]) || (rm[1] > mm[1]) || (rm[2] > mm[2]) || (rm[3] > mm[3]);
      if (__any(grow)) {
#pragma unroll
        for (int r = 0; r < 4; ++r) {
          float mnew = fmaxf(mm[r], rm[r]);
          float alpha = exp2f(mm[r] - mnew);
          float ps = 0.f;
#pragma unroll
          for (int nc = 0; nc < 4; ++nc) {
            float p = exp2f(s[nc][r] - mnew);
            s[nc][r] = p;
            ps += p;
          }
          ll[r] = ll[r] * alpha + ps;
          mm[r] = mnew;
#pragma unroll
          for (int d = 0; d < 4; ++d) o[d][r] *= alpha;
        }
      } else {
#pragma unroll
        for (int r = 0; r < 4; ++r) {
          float ps = 0.f;
#pragma unroll
          for (int nc = 0; nc < 4; ++nc) {
            float p = exp2f(s[nc][r] - mm[r]);
            s[nc][r] = p;
            ps += p;
          }
          ll[r] += ps;
        }
      }
      // P -> per-wave LDS (bf16, swizzled); wave-local, no barrier needed
      bf16_t* Pw = Pl[w];
#pragma unroll
      for (int nc = 0; nc < 4; ++nc)
#pragma unroll
        for (int r = 0; r < 4; ++r) {
          int row = lk * 4 + r;
          int col = nc * 16 + lr;
          int addr = (row * 128 + col * 2) ^ ((row & 7) << 4);
          *(bf16_t*)((char*)Pw + addr) = f2bf(s[nc][r]);
        }
      // PV: P reads (wave-local lgkm order), V from buf[jt&1]
      const char* rbase = (const char*)Vt + ((jt & 1) << 13);
      bf16x8 pa[2];
#pragma unroll
      for (int ks = 0; ks < 2; ++ks) {
        int addr = (lr * 128 + ks * 64 + lk * 16) ^ ((lr & 7) << 4);
        pa[ks] = *(const bf16x8*)((const char*)Pl[w] + addr);
      }
      __builtin_amdgcn_s_setprio(1);
#pragma unroll
      for (int db = 0; db < 4; ++db)
#pragma unroll
        for (int ks = 0; ks < 2; ++ks) {
          int d = db * 16 + lr;
          int addr = (d * 128 + ks * 64 + lk * 16) ^ (((d & 7) ^ ((d >> 3) & 7)) << 4);
          bf16x8 vb = *(const bf16x8*)(rbase + addr);
          o[db] = MFMA16(pa[ks], vb, o[db]);
        }
      __builtin_amdgcn_s_setprio(0);
    };

    int jt = 0;
    for (;;) {
      STEP(jt, vrA, kfA, vrB, kfB);
      if (++jt == jtEnd) break;
      STEP(jt, vrB, kfB, vrA, kfA);
      if (++jt == jtEnd) break;
    }

    // epilogue: finish deferred 16-lane sum of ll, then divide and store
#pragma unroll
    for (int r = 0; r < 4; ++r) ll[r] = red16_sum(ll[r]);
#pragma unroll
    for (int db = 0; db < 4; ++db)
#pragma unroll
      for (int r = 0; r < 4; ++r) {
        int qrow = qr0 + lk * 4 + r;
        float v = o[db][r] / ll[r];
        score[(size_t)(b * 2048 + qrow) * 1024 + h * 64 + db * 16 + lr] = f2bf(v);
      }
  }
}

extern "C" void kernel_launch(void* const* d_in, const int* in_sizes, int n_in,
                              void* d_out, int out_size, void* d_ws, size_t ws_size,
                              hipStream_t stream) {
  const float* X  = (const float*)d_in[0];  // [2,2048,1024]
  const float* Wa = (const float*)d_in[1];  // [1024,3072]
  const float* ba = (const float*)d_in[2];  // [3072]
  const float* Wp = (const float*)d_in[3];  // [1024,1024]
  const float* bp = (const float*)d_in[4];  // [1024]
  float* out = (float*)d_out;               // [2,2048,1024] fp32

  char* ws = (char*)d_ws;
  bf16_t* Xb  = (bf16_t*)ws;                          // 8 MiB (reused as score)
  bf16_t* WaT = (bf16_t*)(ws + (size_t)(8u << 20));   // 6 MiB: W_attn^T [3072][1024]
  bf16_t* WpT = (bf16_t*)(ws + (size_t)(14u << 20));  // 2 MiB: W_proj^T [1024][1024]
  bf16_t* QKV = (bf16_t*)(ws + (size_t)(16u << 20));  // 24 MiB: [4096][3072]
  bf16_t* S_  = Xb;

  k_f32_to_bf16<<<2048, 256, 0, stream>>>(X, Xb, 4096 * 1024 / 8);
  k_transpose_bf16<<<dim3(48, 16), 256, 0, stream>>>(Wa, WaT, 1024, 3072);
  k_transpose_bf16<<<dim3(16, 16), 256, 0, stream>>>(Wp, WpT, 1024, 1024);
  k_gemm_bt<true, true><<<768, 256, 0, stream>>>(Xb, WaT, ba, QKV, 4096, 3072, 1024, 24);
  k_attn<<<512, 256, 0, stream>>>(QKV, S_);
  k_gemm_bt<false, false><<<256, 256, 0, stream>>>(S_, WpT, bp, out, 4096, 1024, 1024, 8);
}